// Round 6
// baseline (419.892 us; speedup 1.0000x reference)
//
#include <hip/hip_runtime.h>

#define BB 4
#define SS 2048
#define DD 1024
#define HH 16
#define DHH 64
#define MM (BB*SS)          // 8192

typedef __bf16 bf16x8 __attribute__((ext_vector_type(8)));
typedef float  f32x4  __attribute__((ext_vector_type(4)));

__device__ __forceinline__ unsigned short f2bf(float x) {
    unsigned int u = __float_as_uint(x);
    u += 0x7FFFu + ((u >> 16) & 1u);          // RNE
    return (unsigned short)(u >> 16);
}

// Async global->LDS, 16B/lane. LDS dst is wave-uniform base + lane*16.
__device__ __forceinline__ void glds16(const __bf16* g, __bf16* l) {
    __builtin_amdgcn_global_load_lds(
        (const __attribute__((address_space(1))) void*)g,
        (__attribute__((address_space(3))) void*)l, 16, 0, 0);
}

// ---------------------------------------------------------------------------
// fp32 -> bf16, all three inputs in one launch.
// ---------------------------------------------------------------------------
__global__ __launch_bounds__(256) void cvt_all(
    const float4* __restrict__ x,  const float4* __restrict__ wq,
    const float4* __restrict__ wo,
    ushort4* __restrict__ xb, ushort4* __restrict__ wqb, ushort4* __restrict__ wob)
{
    int i = blockIdx.x * 256 + threadIdx.x;
    const float4* src; ushort4* dst; int j;
    if (i < 2097152)      { src = x;  dst = xb;  j = i; }
    else if (i < 2883584) { src = wq; dst = wqb; j = i - 2097152; }
    else                  { src = wo; dst = wob; j = i - 2883584; }
    float4 v = src[j];
    ushort4 o;
    o.x = f2bf(v.x); o.y = f2bf(v.y); o.z = f2bf(v.z); o.w = f2bf(v.w);
    dst[j] = o;
}

// ---------------------------------------------------------------------------
// MFMA GEMM (B^T): C[m,n] = sum_k A[m,k] * W[n,k]. 128x128 tile, BK=64,
// 4 waves (2x2 of 64x64), 16x16x32 frags. Staging via global_load_lds
// width=16 into unpadded [128][64] tiles, rotate-by-row granule swizzle.
// ---------------------------------------------------------------------------
__global__ __launch_bounds__(256) void qkv_gemm(
    const __bf16* __restrict__ A,             // [8192,1024] x
    const __bf16* __restrict__ W,             // [3072,1024] W_qkv
    const float* __restrict__ bias,           // [3072]
    __bf16* __restrict__ Qp,                  // [64][2048][64], pre-scaled
    __bf16* __restrict__ Kp,                  // [64][2048][64]
    __bf16* __restrict__ Vp)                  // [64][64][2048] transposed
{
    __shared__ __bf16 smem[16896];            // As(8192) | Bs(8192); CT[128][132]
#define CT(r,c) smem[(r)*132 + (c)]
    __bf16* As = smem;
    __bf16* Bs = smem + 8192;
    const int tid  = threadIdx.x;
    const int m0   = blockIdx.x * 128;
    const int n0   = blockIdx.y * 128;
    const int lane = tid & 63;
    const int wid  = tid >> 6;
    const int fr   = lane & 15;
    const int quad = lane >> 4;
    const int wm   = (wid >> 1) * 64;
    const int wn   = (wid & 1) * 64;

    const int srow = lane >> 3;               // 0..7 within a wave-chunk
    const int sg   = ((lane & 7) - srow) & 7; // swizzled granule to fetch

    f32x4 acc[4][4] = {};

    for (int k0 = 0; k0 < DD; k0 += 64) {
        __syncthreads();
        #pragma unroll
        for (int p = 0; p < 4; ++p) {
            int cidx = p * 4 + wid;           // 0..15 -> rows 8*cidx..+7
            int r = cidx * 8 + srow;
            glds16(A + (size_t)(m0 + r) * DD + k0 + sg * 8, As + cidx * 512);
            glds16(W + (size_t)(n0 + r) * DD + k0 + sg * 8, Bs + cidx * 512);
        }
        __syncthreads();

        bf16x8 af[2][4], bw[2][4];
        #pragma unroll
        for (int kc = 0; kc < 2; ++kc)
            #pragma unroll
            for (int t = 0; t < 4; ++t) {
                int col = ((kc * 4 + quad + fr) & 7) * 8;
                af[kc][t] = *(const bf16x8*)&As[(wm + t*16 + fr) * 64 + col];
                bw[kc][t] = *(const bf16x8*)&Bs[(wn + t*16 + fr) * 64 + col];
            }
        #pragma unroll
        for (int kc = 0; kc < 2; ++kc)
            #pragma unroll
            for (int mt = 0; mt < 4; ++mt)
                #pragma unroll
                for (int nt = 0; nt < 4; ++nt)
                    acc[mt][nt] = __builtin_amdgcn_mfma_f32_16x16x32_bf16(
                        af[kc][mt], bw[kc][nt], acc[mt][nt], 0, 0, 0);
    }

    __syncthreads();                          // staging reads done; reuse smem
    const int t3 = n0 >> 10;                  // 0=q, 1=k, 2=v (uniform/block)
    const int b  = m0 >> 11;
    const int s0 = m0 & (SS - 1);

    float bn[4];
    #pragma unroll
    for (int nt = 0; nt < 4; ++nt) bn[nt] = bias[n0 + wn + nt*16 + fr];

    if (t3 == 2) {
        // V: store tile TRANSPOSED in LDS: CT[n-local][m-local].
        #pragma unroll
        for (int nt = 0; nt < 4; ++nt)
            #pragma unroll
            for (int mt = 0; mt < 4; ++mt)
                #pragma unroll
                for (int i = 0; i < 4; ++i)
                    CT(wn + nt*16 + fr, wm + mt*16 + quad*4 + i) =
                        (__bf16)(acc[mt][nt][i] + bn[nt]);
        __syncthreads();
        const int pn0 = n0 - 2048;
        #pragma unroll
        for (int p = 0; p < 8; ++p) {
            int g = tid + p * 256;
            int r = g >> 4;                   // n-local 0..127
            int c = (g & 15) << 3;            // m-local 0..120
            int pn = pn0 + r, h = pn >> 6, dh = pn & 63;
            *(uint4*)&Vp[((size_t)((b*HH + h)*DHH + dh))*SS + s0 + c] = *(uint4*)&CT(r, c);
        }
    } else {
        __bf16* dst = (t3 == 0) ? Qp : Kp;
        // Q pre-scale folds 1/sqrt(64) AND log2(e) (softmax uses exp2).
        const float qscale = (t3 == 0) ? 0.125f * 1.44269504088896340736f : 1.0f;
        #pragma unroll
        for (int nt = 0; nt < 4; ++nt)
            #pragma unroll
            for (int mt = 0; mt < 4; ++mt)
                #pragma unroll
                for (int i = 0; i < 4; ++i)
                    CT(wm + mt*16 + quad*4 + i, wn + nt*16 + fr) =
                        (__bf16)((acc[mt][nt][i] + bn[nt]) * qscale);
        __syncthreads();
        const int pn0 = (t3 == 0) ? n0 : n0 - 1024;
        #pragma unroll
        for (int p = 0; p < 8; ++p) {
            int g = tid + p * 256;
            int r = g >> 4;                   // m-local (s) 0..127
            int c = (g & 15) << 3;            // n-local 0..120
            int pn = pn0 + c, h = pn >> 6, dh = pn & 63;
            *(uint4*)&dst[((size_t)((b*HH + h))*SS + s0 + r)*DHH + dh] = *(uint4*)&CT(r, c);
        }
    }
#undef CT
}

__global__ __launch_bounds__(256) void out_gemm(
    const __bf16* __restrict__ A,             // [8192,1024] O bf16
    const __bf16* __restrict__ W,             // [1024,1024] W_out bf16
    const float* __restrict__ bias,           // [1024]
    float* __restrict__ out)                  // [8192,1024] fp32
{
    __shared__ __bf16 smem[16384];            // As(8192) | Bs(8192)
    __bf16* As = smem;
    __bf16* Bs = smem + 8192;
    const int tid  = threadIdx.x;
    const int m0   = blockIdx.x * 128;
    const int n0   = blockIdx.y * 128;
    const int lane = tid & 63;
    const int wid  = tid >> 6;
    const int fr   = lane & 15;
    const int quad = lane >> 4;
    const int wm   = (wid >> 1) * 64;
    const int wn   = (wid & 1) * 64;

    const int srow = lane >> 3;
    const int sg   = ((lane & 7) - srow) & 7;

    f32x4 acc[4][4] = {};

    for (int k0 = 0; k0 < DD; k0 += 64) {
        __syncthreads();
        #pragma unroll
        for (int p = 0; p < 4; ++p) {
            int cidx = p * 4 + wid;
            int r = cidx * 8 + srow;
            glds16(A + (size_t)(m0 + r) * DD + k0 + sg * 8, As + cidx * 512);
            glds16(W + (size_t)(n0 + r) * DD + k0 + sg * 8, Bs + cidx * 512);
        }
        __syncthreads();

        bf16x8 af[2][4], bw[2][4];
        #pragma unroll
        for (int kc = 0; kc < 2; ++kc)
            #pragma unroll
            for (int t = 0; t < 4; ++t) {
                int col = ((kc * 4 + quad + fr) & 7) * 8;
                af[kc][t] = *(const bf16x8*)&As[(wm + t*16 + fr) * 64 + col];
                bw[kc][t] = *(const bf16x8*)&Bs[(wn + t*16 + fr) * 64 + col];
            }
        #pragma unroll
        for (int kc = 0; kc < 2; ++kc)
            #pragma unroll
            for (int mt = 0; mt < 4; ++mt)
                #pragma unroll
                for (int nt = 0; nt < 4; ++nt)
                    acc[mt][nt] = __builtin_amdgcn_mfma_f32_16x16x32_bf16(
                        af[kc][mt], bw[kc][nt], acc[mt][nt], 0, 0, 0);
    }

    #pragma unroll
    for (int nt = 0; nt < 4; ++nt) {
        int n  = n0 + wn + nt*16 + fr;
        float bnv = bias[n];
        #pragma unroll
        for (int mt = 0; mt < 4; ++mt) {
            #pragma unroll
            for (int i = 0; i < 4; ++i) {
                int m = m0 + wm + mt*16 + quad*4 + i;
                out[(size_t)m * DD + n] = acc[mt][nt][i] + bnv;
            }
        }
    }
}

// ---------------------------------------------------------------------------
// MFMA flash attention v5. Grid (8 q-tiles, 64 bh), block 256 = 4 waves,
// each wave owns 64 q-rows. KEY TRICK: compute S^T = K * Q^T (A=K-frag,
// B=Q-frag; a Q B-frag is byte-identical to its A-frag, loaded straight
// from global — no Q LDS staging). S^T's C-layout puts q in the lane dim
// and key in the reg dim, so each lane's 4 P values are CONSECUTIVE key
// columns of P[q][key] -> one ds_write_b64 each (16 stores/round vs 64).
// PV: A=P (b128 reads), B=VT -> O in standard C-layout. 64-key rounds via
// global_load_lds + rotate swizzle. exp2 softmax (log2e folded into Q),
// no max-subtraction, deferred denominator.
// LDS: Ks 8K + VT 8K + Ps 36K + Ls 1K = 53K -> 3 blocks/CU.
// ---------------------------------------------------------------------------
__global__ __launch_bounds__(256, 3) void attn_mfma(
    const __bf16* __restrict__ Qp,            // [bh][s][dh], pre-scaled
    const __bf16* __restrict__ Kp,            // [bh][s][dh]
    const __bf16* __restrict__ Vp,            // [bh][dh][s]  (transposed)
    __bf16* __restrict__ Op)                  // [8192][1024] (b,s,h*dh)
{
    __shared__ __bf16 Ks[64 * 64];            // swizzled rot-8
    __shared__ __bf16 VT[64 * 64];            // swizzled rot-8
    __shared__ __bf16 Ps[256][72];            // P, then O staging
    __shared__ float  Ls[256];                // denominators

    const int tid  = threadIdx.x;
    const int q0   = blockIdx.x * 256;
    const int bh   = blockIdx.y;
    const size_t base = (size_t)bh * SS * DHH;
    const int lane = tid & 63;
    const int wid  = tid >> 6;
    const int fr   = lane & 15;
    const int quad = lane >> 4;
    const int wrow = wid * 64;                // this wave's q-rows in tile

    const int srow = lane >> 3;
    const int sg   = ((lane & 7) - srow) & 7;

    // Q B-frags straight from global (B[k=d][n=q] bytes == A-frag bytes).
    bf16x8 aq[4][2];
    #pragma unroll
    for (int nt = 0; nt < 4; ++nt)
        #pragma unroll
        for (int kc = 0; kc < 2; ++kc)
            aq[nt][kc] = *(const bf16x8*)
                (Qp + base + (size_t)(q0 + wrow + nt*16 + fr) * DHH + kc*32 + quad*8);

    f32x4 o[4][4] = {};
    float lp[4] = {};

    for (int kt = 0; kt < SS; kt += 64) {
        __syncthreads();                      // prior round's Ks/VT reads done
        #pragma unroll
        for (int p = 0; p < 2; ++p) {
            int cidx = p * 4 + wid;           // 0..7 -> rows 8*cidx..+7
            int r = cidx * 8 + srow;
            glds16(Kp + base + (size_t)(kt + r) * DHH + sg * 8, Ks + cidx * 512);
            glds16(Vp + base + (size_t)r * SS + kt + sg * 8, VT + cidx * 512);
        }
        __syncthreads();

        // S^T = K Q^T : D[key=mt*16+quad*4+i][q=wrow+nt*16+fr].
        #pragma unroll
        for (int mt = 0; mt < 4; ++mt) {
            bf16x8 bk[2];
            #pragma unroll
            for (int kc = 0; kc < 2; ++kc)
                bk[kc] = *(const bf16x8*)
                    &Ks[(mt*16 + fr) * 64 + ((kc*4 + quad + fr) & 7) * 8];
            f32x4 s[4] = {};
            #pragma unroll
            for (int nt = 0; nt < 4; ++nt)
                #pragma unroll
                for (int kc = 0; kc < 2; ++kc)
                    s[nt] = __builtin_amdgcn_mfma_f32_16x16x32_bf16(
                        bk[kc], aq[nt][kc], s[nt], 0, 0, 0);
            #pragma unroll
            for (int nt = 0; nt < 4; ++nt) {
                float e0 = __builtin_amdgcn_exp2f(s[nt][0]);
                float e1 = __builtin_amdgcn_exp2f(s[nt][1]);
                float e2 = __builtin_amdgcn_exp2f(s[nt][2]);
                float e3 = __builtin_amdgcn_exp2f(s[nt][3]);
                lp[nt] += (e0 + e1) + (e2 + e3);
                ushort4 pk;
                pk.x = f2bf(e0); pk.y = f2bf(e1);
                pk.z = f2bf(e2); pk.w = f2bf(e3);
                *(ushort4*)&Ps[wrow + nt*16 + fr][mt*16 + quad*4] = pk;
            }
        }

        // O += P V  (P rows wave-private; same-wave DS ordering).
        #pragma unroll
        for (int mt = 0; mt < 4; ++mt) {
            bf16x8 ap[2];
            #pragma unroll
            for (int kc = 0; kc < 2; ++kc)
                ap[kc] = *(const bf16x8*)&Ps[wrow + mt*16 + fr][kc*32 + quad*8];
            #pragma unroll
            for (int nt = 0; nt < 4; ++nt)
                #pragma unroll
                for (int kc = 0; kc < 2; ++kc) {
                    bf16x8 bv = *(const bf16x8*)
                        &VT[(nt*16 + fr) * 64 + ((kc*4 + quad + fr) & 7) * 8];
                    o[mt][nt] = __builtin_amdgcn_mfma_f32_16x16x32_bf16(
                        ap[kc], bv, o[mt][nt], 0, 0, 0);
                }
        }
    }

    // Denominators: lane's lp[nt] covers keys {quad*4+i, +16mt, rounds} for
    // q-row (nt,fr); reduce across the 4 quads, park in LDS for relayout.
    #pragma unroll
    for (int nt = 0; nt < 4; ++nt) {
        float v = lp[nt];
        v += __shfl_xor(v, 16);
        v += __shfl_xor(v, 32);
        Ls[wrow + nt*16 + fr] = v;            // all quads write same value
    }

    // Normalize O (C-layout rows = q) and stage to Ps for coalesced write.
    #pragma unroll
    for (int mt = 0; mt < 4; ++mt)
        #pragma unroll
        for (int i = 0; i < 4; ++i) {
            float inv = 1.0f / Ls[wrow + mt*16 + quad*4 + i];
            #pragma unroll
            for (int nt = 0; nt < 4; ++nt)
                Ps[wrow + mt*16 + quad*4 + i][nt*16 + fr] = (__bf16)(o[mt][nt][i] * inv);
        }
    __syncthreads();

    const int b = bh >> 4, h = bh & (HH - 1);
    #pragma unroll
    for (int p = 0; p < 8; ++p) {
        int g = tid + p * 256;
        int r = g >> 3;
        int c = (g & 7) << 3;
        *(uint4*)&Op[((size_t)(b*SS + q0 + r))*DD + h*DHH + c] = *(uint4*)&Ps[r][c];
    }
}

// ---------------------------------------------------------------------------

extern "C" void kernel_launch(void* const* d_in, const int* in_sizes, int n_in,
                              void* d_out, int out_size, void* d_ws, size_t ws_size,
                              hipStream_t stream)
{
    const float* x     = (const float*)d_in[0];
    const float* W_qkv = (const float*)d_in[1];
    const float* b_qkv = (const float*)d_in[2];
    const float* W_out = (const float*)d_in[3];
    const float* b_out = (const float*)d_in[4];
    float* out = (float*)d_out;

    __bf16* ws  = (__bf16*)d_ws;
    __bf16* xb  = ws;                          // 8388608
    __bf16* wqb = xb  + (size_t)8388608;       // 3145728
    __bf16* wob = wqb + (size_t)3145728;       // 1048576
    __bf16* qp  = wob + (size_t)1048576;       // 8388608 each
    __bf16* kp  = qp  + (size_t)8388608;
    __bf16* vp  = kp  + (size_t)8388608;
    __bf16* op  = vp  + (size_t)8388608;

    cvt_all<<<12288, 256, 0, stream>>>(
        (const float4*)x, (const float4*)W_qkv, (const float4*)W_out,
        (ushort4*)xb, (ushort4*)wqb, (ushort4*)wob);

    qkv_gemm<<<dim3(MM/128, 3*DD/128), 256, 0, stream>>>(xb, wqb, b_qkv, qp, kp, vp);
    attn_mfma<<<dim3(SS/256, BB*HH), 256, 0, stream>>>(qp, kp, vp, op);
    out_gemm<<<dim3(MM/128, DD/128), 256, 0, stream>>>(op, wob, b_out, out);
}

// Round 7
// 265.385 us; speedup vs baseline: 1.5822x; 1.5822x over previous
//
#include <hip/hip_runtime.h>

#define BB 4
#define SS 2048
#define DD 1024
#define HH 16
#define DHH 64
#define MM (BB*SS)          // 8192

typedef __bf16 bf16x8 __attribute__((ext_vector_type(8)));
typedef __bf16 bf16x4 __attribute__((ext_vector_type(4)));
typedef float  f32x4  __attribute__((ext_vector_type(4)));

__device__ __forceinline__ unsigned short f2bf(float x) {
    unsigned int u = __float_as_uint(x);
    u += 0x7FFFu + ((u >> 16) & 1u);          // RNE
    return (unsigned short)(u >> 16);
}

// Async global->LDS, 16B/lane. LDS dst is wave-uniform base + lane*16.
__device__ __forceinline__ void glds16(const __bf16* g, __bf16* l) {
    __builtin_amdgcn_global_load_lds(
        (const __attribute__((address_space(1))) void*)g,
        (__attribute__((address_space(3))) void*)l, 16, 0, 0);
}

// ---------------------------------------------------------------------------
// fp32 -> bf16, all three inputs in one launch.
// ---------------------------------------------------------------------------
__global__ __launch_bounds__(256) void cvt_all(
    const float4* __restrict__ x,  const float4* __restrict__ wq,
    const float4* __restrict__ wo,
    ushort4* __restrict__ xb, ushort4* __restrict__ wqb, ushort4* __restrict__ wob)
{
    int i = blockIdx.x * 256 + threadIdx.x;
    const float4* src; ushort4* dst; int j;
    if (i < 2097152)      { src = x;  dst = xb;  j = i; }
    else if (i < 2883584) { src = wq; dst = wqb; j = i - 2097152; }
    else                  { src = wo; dst = wob; j = i - 2883584; }
    float4 v = src[j];
    ushort4 o;
    o.x = f2bf(v.x); o.y = f2bf(v.y); o.z = f2bf(v.z); o.w = f2bf(v.w);
    dst[j] = o;
}

// ---------------------------------------------------------------------------
// MFMA GEMM (B^T): C[m,n] = sum_k A[m,k] * W[n,k]. 128x128 tile, BK=64,
// 4 waves (2x2 of 64x64), 16x16x32 frags. Staging via global_load_lds
// width=16 into unpadded [128][64] tiles, rotate-by-row granule swizzle
// (2-way bank aliasing per 16-lane phase = free).
// ---------------------------------------------------------------------------
__global__ __launch_bounds__(256) void qkv_gemm(
    const __bf16* __restrict__ A,             // [8192,1024] x
    const __bf16* __restrict__ W,             // [3072,1024] W_qkv
    const float* __restrict__ bias,           // [3072]
    __bf16* __restrict__ Qp,                  // [64][2048][64], pre-scaled
    __bf16* __restrict__ Kp,                  // [64][2048][64]
    __bf16* __restrict__ Vp)                  // [64][64][2048] transposed
{
    __shared__ __bf16 smem[16896];            // As(8192) | Bs(8192); CT[128][132]
#define CT(r,c) smem[(r)*132 + (c)]
    __bf16* As = smem;
    __bf16* Bs = smem + 8192;
    const int tid  = threadIdx.x;
    const int m0   = blockIdx.x * 128;
    const int n0   = blockIdx.y * 128;
    const int lane = tid & 63;
    const int wid  = tid >> 6;
    const int fr   = lane & 15;
    const int quad = lane >> 4;
    const int wm   = (wid >> 1) * 64;
    const int wn   = (wid & 1) * 64;

    const int srow = lane >> 3;               // 0..7 within a wave-chunk
    const int sg   = ((lane & 7) - srow) & 7; // swizzled granule to fetch

    f32x4 acc[4][4] = {};

    for (int k0 = 0; k0 < DD; k0 += 64) {
        __syncthreads();
        #pragma unroll
        for (int p = 0; p < 4; ++p) {
            int cidx = p * 4 + wid;           // 0..15 -> rows 8*cidx..+7
            int r = cidx * 8 + srow;
            glds16(A + (size_t)(m0 + r) * DD + k0 + sg * 8, As + cidx * 512);
            glds16(W + (size_t)(n0 + r) * DD + k0 + sg * 8, Bs + cidx * 512);
        }
        __syncthreads();

        bf16x8 af[2][4], bw[2][4];
        #pragma unroll
        for (int kc = 0; kc < 2; ++kc)
            #pragma unroll
            for (int t = 0; t < 4; ++t) {
                int col = ((kc * 4 + quad + fr) & 7) * 8;
                af[kc][t] = *(const bf16x8*)&As[(wm + t*16 + fr) * 64 + col];
                bw[kc][t] = *(const bf16x8*)&Bs[(wn + t*16 + fr) * 64 + col];
            }
        #pragma unroll
        for (int kc = 0; kc < 2; ++kc)
            #pragma unroll
            for (int mt = 0; mt < 4; ++mt)
                #pragma unroll
                for (int nt = 0; nt < 4; ++nt)
                    acc[mt][nt] = __builtin_amdgcn_mfma_f32_16x16x32_bf16(
                        af[kc][mt], bw[kc][nt], acc[mt][nt], 0, 0, 0);
    }

    __syncthreads();                          // staging reads done; reuse smem
    const int t3 = n0 >> 10;                  // 0=q, 1=k, 2=v (uniform/block)
    const int b  = m0 >> 11;
    const int s0 = m0 & (SS - 1);

    float bn[4];
    #pragma unroll
    for (int nt = 0; nt < 4; ++nt) bn[nt] = bias[n0 + wn + nt*16 + fr];

    if (t3 == 2) {
        // V: store tile TRANSPOSED in LDS: CT[n-local][m-local], packed b64.
        #pragma unroll
        for (int nt = 0; nt < 4; ++nt)
            #pragma unroll
            for (int mt = 0; mt < 4; ++mt) {
                f32x4 t;
                #pragma unroll
                for (int i = 0; i < 4; ++i) t[i] = acc[mt][nt][i] + bn[nt];
                *(bf16x4*)&CT(wn + nt*16 + fr, wm + mt*16 + quad*4) =
                    __builtin_convertvector(t, bf16x4);
            }
        __syncthreads();
        const int pn0 = n0 - 2048;
        #pragma unroll
        for (int p = 0; p < 8; ++p) {
            int g = tid + p * 256;
            int r = g >> 4;                   // n-local 0..127
            int c = (g & 15) << 3;            // m-local 0..120
            int pn = pn0 + r, h = pn >> 6, dh = pn & 63;
            *(uint4*)&Vp[((size_t)((b*HH + h)*DHH + dh))*SS + s0 + c] = *(uint4*)&CT(r, c);
        }
    } else {
        __bf16* dst = (t3 == 0) ? Qp : Kp;
        // Q pre-scale folds 1/sqrt(64) AND log2(e) (softmax uses exp2).
        const float qscale = (t3 == 0) ? 0.125f * 1.44269504088896340736f : 1.0f;
        #pragma unroll
        for (int nt = 0; nt < 4; ++nt)
            #pragma unroll
            for (int mt = 0; mt < 4; ++mt)
                #pragma unroll
                for (int i = 0; i < 4; ++i)
                    CT(wm + mt*16 + quad*4 + i, wn + nt*16 + fr) =
                        (__bf16)((acc[mt][nt][i] + bn[nt]) * qscale);
        __syncthreads();
        const int pn0 = (t3 == 0) ? n0 : n0 - 1024;
        #pragma unroll
        for (int p = 0; p < 8; ++p) {
            int g = tid + p * 256;
            int r = g >> 4;                   // m-local (s) 0..127
            int c = (g & 15) << 3;            // n-local 0..120
            int pn = pn0 + c, h = pn >> 6, dh = pn & 63;
            *(uint4*)&dst[((size_t)((b*HH + h))*SS + s0 + r)*DHH + dh] = *(uint4*)&CT(r, c);
        }
    }
#undef CT
}

__global__ __launch_bounds__(256) void out_gemm(
    const __bf16* __restrict__ A,             // [8192,1024] O bf16
    const __bf16* __restrict__ W,             // [1024,1024] W_out bf16
    const float* __restrict__ bias,           // [1024]
    float* __restrict__ out)                  // [8192,1024] fp32
{
    __shared__ __bf16 smem[16384];            // As(8192) | Bs(8192)
    __bf16* As = smem;
    __bf16* Bs = smem + 8192;
    const int tid  = threadIdx.x;
    const int m0   = blockIdx.x * 128;
    const int n0   = blockIdx.y * 128;
    const int lane = tid & 63;
    const int wid  = tid >> 6;
    const int fr   = lane & 15;
    const int quad = lane >> 4;
    const int wm   = (wid >> 1) * 64;
    const int wn   = (wid & 1) * 64;

    const int srow = lane >> 3;
    const int sg   = ((lane & 7) - srow) & 7;

    f32x4 acc[4][4] = {};

    for (int k0 = 0; k0 < DD; k0 += 64) {
        __syncthreads();
        #pragma unroll
        for (int p = 0; p < 4; ++p) {
            int cidx = p * 4 + wid;
            int r = cidx * 8 + srow;
            glds16(A + (size_t)(m0 + r) * DD + k0 + sg * 8, As + cidx * 512);
            glds16(W + (size_t)(n0 + r) * DD + k0 + sg * 8, Bs + cidx * 512);
        }
        __syncthreads();

        bf16x8 af[2][4], bw[2][4];
        #pragma unroll
        for (int kc = 0; kc < 2; ++kc)
            #pragma unroll
            for (int t = 0; t < 4; ++t) {
                int col = ((kc * 4 + quad + fr) & 7) * 8;
                af[kc][t] = *(const bf16x8*)&As[(wm + t*16 + fr) * 64 + col];
                bw[kc][t] = *(const bf16x8*)&Bs[(wn + t*16 + fr) * 64 + col];
            }
        #pragma unroll
        for (int kc = 0; kc < 2; ++kc)
            #pragma unroll
            for (int mt = 0; mt < 4; ++mt)
                #pragma unroll
                for (int nt = 0; nt < 4; ++nt)
                    acc[mt][nt] = __builtin_amdgcn_mfma_f32_16x16x32_bf16(
                        af[kc][mt], bw[kc][nt], acc[mt][nt], 0, 0, 0);
    }

    #pragma unroll
    for (int nt = 0; nt < 4; ++nt) {
        int n  = n0 + wn + nt*16 + fr;
        float bnv = bias[n];
        #pragma unroll
        for (int mt = 0; mt < 4; ++mt) {
            #pragma unroll
            for (int i = 0; i < 4; ++i) {
                int m = m0 + wm + mt*16 + quad*4 + i;
                out[(size_t)m * DD + n] = acc[mt][nt][i] + bnv;
            }
        }
    }
}

// ---------------------------------------------------------------------------
// MFMA flash attention v6 = v5 structure (S^T = K*Q^T trick, 64-key rounds,
// glds+swizzle staging, exp2 softmax, deferred denominator) with the R4-
// verified register config: __launch_bounds__(256,2). R6's (256,3) made the
// allocator target 85 VGPRs and spill the O accumulator to scratch
// (WRITE_SIZE 479 MB). P-pack uses v_cvt_pk_bf16_f32 via convertvector.
// LDS: Ks 8K + VT 8K + Ps 36K + Ls 1K = 53K.
// ---------------------------------------------------------------------------
__global__ __launch_bounds__(256, 2) void attn_mfma(
    const __bf16* __restrict__ Qp,            // [bh][s][dh], pre-scaled
    const __bf16* __restrict__ Kp,            // [bh][s][dh]
    const __bf16* __restrict__ Vp,            // [bh][dh][s]  (transposed)
    __bf16* __restrict__ Op)                  // [8192][1024] (b,s,h*dh)
{
    __shared__ __bf16 Ks[64 * 64];            // swizzled rot-8
    __shared__ __bf16 VT[64 * 64];            // swizzled rot-8
    __shared__ __bf16 Ps[256][72];            // P, then O staging
    __shared__ float  Ls[256];                // denominators

    const int tid  = threadIdx.x;
    const int q0   = blockIdx.x * 256;
    const int bh   = blockIdx.y;
    const size_t base = (size_t)bh * SS * DHH;
    const int lane = tid & 63;
    const int wid  = tid >> 6;
    const int fr   = lane & 15;
    const int quad = lane >> 4;
    const int wrow = wid * 64;                // this wave's q-rows in tile

    const int srow = lane >> 3;
    const int sg   = ((lane & 7) - srow) & 7;

    // Q B-frags straight from global (B[k=d][n=q] bytes == A-frag bytes).
    bf16x8 aq[4][2];
    #pragma unroll
    for (int nt = 0; nt < 4; ++nt)
        #pragma unroll
        for (int kc = 0; kc < 2; ++kc)
            aq[nt][kc] = *(const bf16x8*)
                (Qp + base + (size_t)(q0 + wrow + nt*16 + fr) * DHH + kc*32 + quad*8);

    f32x4 o[4][4] = {};
    float lp[4] = {};

    for (int kt = 0; kt < SS; kt += 64) {
        __syncthreads();                      // prior round's Ks/VT reads done
        #pragma unroll
        for (int p = 0; p < 2; ++p) {
            int cidx = p * 4 + wid;           // 0..7 -> rows 8*cidx..+7
            int r = cidx * 8 + srow;
            glds16(Kp + base + (size_t)(kt + r) * DHH + sg * 8, Ks + cidx * 512);
            glds16(Vp + base + (size_t)r * SS + kt + sg * 8, VT + cidx * 512);
        }
        __syncthreads();

        // S^T = K Q^T : D[key=mt*16+quad*4+i][q=wrow+nt*16+fr].
        #pragma unroll
        for (int mt = 0; mt < 4; ++mt) {
            bf16x8 bk[2];
            #pragma unroll
            for (int kc = 0; kc < 2; ++kc)
                bk[kc] = *(const bf16x8*)
                    &Ks[(mt*16 + fr) * 64 + ((kc*4 + quad + fr) & 7) * 8];
            f32x4 s[4] = {};
            #pragma unroll
            for (int nt = 0; nt < 4; ++nt)
                #pragma unroll
                for (int kc = 0; kc < 2; ++kc)
                    s[nt] = __builtin_amdgcn_mfma_f32_16x16x32_bf16(
                        bk[kc], aq[nt][kc], s[nt], 0, 0, 0);
            #pragma unroll
            for (int nt = 0; nt < 4; ++nt) {
                f32x4 ev;
                ev[0] = __builtin_amdgcn_exp2f(s[nt][0]);
                ev[1] = __builtin_amdgcn_exp2f(s[nt][1]);
                ev[2] = __builtin_amdgcn_exp2f(s[nt][2]);
                ev[3] = __builtin_amdgcn_exp2f(s[nt][3]);
                lp[nt] += (ev[0] + ev[1]) + (ev[2] + ev[3]);
                *(bf16x4*)&Ps[wrow + nt*16 + fr][mt*16 + quad*4] =
                    __builtin_convertvector(ev, bf16x4);
            }
        }

        // O += P V  (P rows wave-private; same-wave DS ordering).
        #pragma unroll
        for (int mt = 0; mt < 4; ++mt) {
            bf16x8 ap[2];
            #pragma unroll
            for (int kc = 0; kc < 2; ++kc)
                ap[kc] = *(const bf16x8*)&Ps[wrow + mt*16 + fr][kc*32 + quad*8];
            #pragma unroll
            for (int nt = 0; nt < 4; ++nt)
                #pragma unroll
                for (int kc = 0; kc < 2; ++kc) {
                    bf16x8 bv = *(const bf16x8*)
                        &VT[(nt*16 + fr) * 64 + ((kc*4 + quad + fr) & 7) * 8];
                    o[mt][nt] = __builtin_amdgcn_mfma_f32_16x16x32_bf16(
                        ap[kc], bv, o[mt][nt], 0, 0, 0);
                }
        }
    }

    // Denominators: lane's lp[nt] covers keys {quad*4+i, 16mt, rounds} for
    // q-row (nt,fr); reduce across the 4 quads, park in LDS for relayout.
    #pragma unroll
    for (int nt = 0; nt < 4; ++nt) {
        float v = lp[nt];
        v += __shfl_xor(v, 16);
        v += __shfl_xor(v, 32);
        Ls[wrow + nt*16 + fr] = v;            // all quads write same value
    }

    // Normalize O (C-layout rows = q) and stage to Ps for coalesced write.
    #pragma unroll
    for (int mt = 0; mt < 4; ++mt)
        #pragma unroll
        for (int i = 0; i < 4; ++i) {
            float inv = 1.0f / Ls[wrow + mt*16 + quad*4 + i];
            #pragma unroll
            for (int nt = 0; nt < 4; ++nt)
                Ps[wrow + mt*16 + quad*4 + i][nt*16 + fr] = (__bf16)(o[mt][nt][i] * inv);
        }
    __syncthreads();

    const int b = bh >> 4, h = bh & (HH - 1);
    #pragma unroll
    for (int p = 0; p < 8; ++p) {
        int g = tid + p * 256;
        int r = g >> 3;
        int c = (g & 7) << 3;
        *(uint4*)&Op[((size_t)(b*SS + q0 + r))*DD + h*DHH + c] = *(uint4*)&Ps[r][c];
    }
}

// ---------------------------------------------------------------------------

extern "C" void kernel_launch(void* const* d_in, const int* in_sizes, int n_in,
                              void* d_out, int out_size, void* d_ws, size_t ws_size,
                              hipStream_t stream)
{
    const float* x     = (const float*)d_in[0];
    const float* W_qkv = (const float*)d_in[1];
    const float* b_qkv = (const float*)d_in[2];
    const float* W_out = (const float*)d_in[3];
    const float* b_out = (const float*)d_in[4];
    float* out = (float*)d_out;

    __bf16* ws  = (__bf16*)d_ws;
    __bf16* xb  = ws;                          // 8388608
    __bf16* wqb = xb  + (size_t)8388608;       // 3145728
    __bf16* wob = wqb + (size_t)3145728;       // 1048576
    __bf16* qp  = wob + (size_t)1048576;       // 8388608 each
    __bf16* kp  = qp  + (size_t)8388608;
    __bf16* vp  = kp  + (size_t)8388608;
    __bf16* op  = vp  + (size_t)8388608;

    cvt_all<<<12288, 256, 0, stream>>>(
        (const float4*)x, (const float4*)W_qkv, (const float4*)W_out,
        (ushort4*)xb, (ushort4*)wqb, (ushort4*)wob);

    qkv_gemm<<<dim3(MM/128, 3*DD/128), 256, 0, stream>>>(xb, wqb, b_qkv, qp, kp, vp);
    attn_mfma<<<dim3(SS/256, BB*HH), 256, 0, stream>>>(qp, kp, vp, op);
    out_gemm<<<dim3(MM/128, DD/128), 256, 0, stream>>>(op, wob, b_out, out);
}